// Round 1
// baseline (214.515 us; speedup 1.0000x reference)
//
#include <hip/hip_runtime.h>
#include <stdint.h>

#define B_ROWS 128
#define V_COLS 128000
#define BLOCKS_PER_ROW 4
#define SLICE (V_COLS / BLOCKS_PER_ROW)   // 32000
#define CAP 2048
#define K1_THREADS 256

// monotone transform: larger float <-> larger uint
__device__ __forceinline__ uint32_t f2u(float f) {
    uint32_t x = __float_as_uint(f);
    return (x & 0x80000000u) ? ~x : (x | 0x80000000u);
}
__device__ __forceinline__ float u2f(uint32_t u) {
    uint32_t x = (u & 0x80000000u) ? (u & 0x7FFFFFFFu) : ~u;
    return __uint_as_float(x);
}

// descending bitonic sort of (u, idx) in LDS; ties: larger idx first
// (matches stable ascending argsort of the reference when viewed ascending)
__device__ __forceinline__ void bitonic_sort_desc(uint32_t* su, uint32_t* si, int NP) {
    const int tid = threadIdx.x;
    const int nth = blockDim.x;
    for (int ksz = 2; ksz <= NP; ksz <<= 1) {
        for (int j = ksz >> 1; j > 0; j >>= 1) {
            __syncthreads();
            for (int i = tid; i < NP; i += nth) {
                int ixj = i ^ j;
                if (ixj > i) {
                    uint32_t ua = su[i], ub = su[ixj];
                    uint32_t ia = si[i], ib = si[ixj];
                    bool a_lt = (ua < ub) || (ua == ub && ia < ib);
                    if (((i & ksz) == 0) ? a_lt : !a_lt) {
                        su[i] = ub; su[ixj] = ua;
                        si[i] = ib; si[ixj] = ia;
                    }
                }
            }
        }
    }
    __syncthreads();
}

__device__ __forceinline__ void compact_topk(uint32_t* su, uint32_t* si,
                                             int* s_cnt, uint32_t* s_thr) {
    __syncthreads();
    int n = *s_cnt; if (n > CAP) n = CAP;
    int NP = 64; while (NP < n) NP <<= 1;
    for (int i = n + (int)threadIdx.x; i < NP; i += (int)blockDim.x) {
        su[i] = 0u; si[i] = 0xFFFFFFFFu;
    }
    bitonic_sort_desc(su, si, NP);   // leading barrier inside covers the padding writes
    if (threadIdx.x == 0) { *s_cnt = 64; *s_thr = su[63]; }
    __syncthreads();
}

// K1: per (row, quarter) block: exact top-64 of its 32000-element slice
__global__ __launch_bounds__(K1_THREADS) void topk_partial_kernel(
    const float* __restrict__ logits,
    uint32_t* __restrict__ out_u, uint32_t* __restrict__ out_idx)
{
    __shared__ uint32_t s_u[CAP];
    __shared__ uint32_t s_idx[CAP];
    __shared__ int s_cnt;
    __shared__ uint32_t s_thr;
    __shared__ int s_flag;

    const int blk = blockIdx.x;
    const int row = blk >> 2;
    const int q = blk & 3;
    const int tid = threadIdx.x;
    const int lane = tid & 63;
    const float4* src = (const float4*)(logits + (size_t)row * V_COLS + (size_t)q * SLICE);

    if (tid == 0) { s_cnt = 0; s_thr = 0u; s_flag = 0; }
    __syncthreads();

    const int n4 = SLICE / 4;              // 8000 float4 per slice
    const int iters = (n4 + K1_THREADS - 1) / K1_THREADS;  // 32

    for (int it = 0; it < iters; ++it) {
        int i = it * K1_THREADS + tid;
        bool valid = i < n4;
        float4 v4 = make_float4(0.f, 0.f, 0.f, 0.f);
        if (valid) v4 = src[i];
        uint32_t thr = s_thr;
        #pragma unroll
        for (int e = 0; e < 4; ++e) {
            float f = (e == 0) ? v4.x : (e == 1) ? v4.y : (e == 2) ? v4.z : v4.w;
            uint32_t u = f2u(f);
            bool pred = valid && (u >= thr);
            unsigned long long mask = __ballot(pred);
            if (mask) {
                int leader = __ffsll(mask) - 1;
                int nact = __popcll(mask);
                int base = 0;
                if (lane == leader) base = atomicAdd(&s_cnt, nact);
                base = __shfl(base, leader, 64);
                if (pred) {
                    int off = __popcll(mask & ((1ull << lane) - 1ull));
                    int pos = base + off;
                    if (pos < CAP) {
                        s_u[pos] = u;
                        s_idx[pos] = (uint32_t)(q * SLICE + i * 4 + e);
                    }
                }
            }
        }
        __syncthreads();
        if (tid == 0) s_flag = (s_cnt > CAP - K1_THREADS * 4) ? 1 : 0;
        __syncthreads();
        if (s_flag) compact_topk(s_u, s_idx, &s_cnt, &s_thr);
    }
    compact_topk(s_u, s_idx, &s_cnt, &s_thr);
    if (tid < 64) {
        out_u[blk * 64 + tid]  = s_u[tid];
        out_idx[blk * 64 + tid] = s_idx[tid];
    }
}

// K2: one block per row: merge 4x64 candidates, sort, top-k/top-p filter, sample.
__global__ __launch_bounds__(256) void sample_kernel(
    const uint32_t* __restrict__ in_u, const uint32_t* __restrict__ in_idx,
    const int* __restrict__ kk, const float* __restrict__ pp,
    const float* __restrict__ noise, int* __restrict__ out)
{
    __shared__ uint32_t s_u[256];
    __shared__ uint32_t s_idx[256];
    const int row = blockIdx.x;
    const int tid = threadIdx.x;

    s_u[tid] = in_u[row * 256 + tid];
    s_idx[tid] = in_idx[row * 256 + tid];
    bitonic_sort_desc(s_u, s_idx, 256);   // leading barrier covers loads

    if (tid < 64) {
        const int lane = tid;
        float v = u2f(s_u[lane]);             // lane j holds (j+1)-th largest of row
        uint32_t tok = s_idx[lane];
        int k = kk[row];
        if (k > 64) k = 64;                    // safety; setup guarantees k<=63
        float p = pp[row];

        // top-k: threshold = k-th largest; keep v >= thr (ties kept, as reference)
        float thrv = __shfl(v, k - 1, 64);
        bool kept = v >= thrv;
        float m = __shfl(v, 0, 64);            // row max
        float e = kept ? expf(v - m) : 0.0f;

        // softmax denom over kept
        float denom = e;
        #pragma unroll
        for (int off = 1; off < 64; off <<= 1) denom += __shfl_xor(denom, off, 64);
        float prob = e / denom;

        // ascending-inclusive cumsum == suffix sum over descending lanes
        float cums = prob;
        #pragma unroll
        for (int off = 1; off < 64; off <<= 1) {
            float o = __shfl_down(cums, off, 64);
            cums += (lane + off < 64) ? o : 0.0f;
        }
        // top-p: mask cumsum <= 1-p, but always keep the max (lane 0)
        bool masked = (cums <= 1.0f - p) && (lane != 0);
        bool surv = kept && !masked;

        // renormalize over survivors
        float e2 = surv ? e : 0.0f;
        float denom2 = e2;
        #pragma unroll
        for (int off = 1; off < 64; off <<= 1) denom2 += __shfl_xor(denom2, off, 64);

        float score = -1.0f;
        uint32_t bidx = 0xFFFFFFFFu;
        if (surv) {
            float nz = noise[(size_t)row * V_COLS + tok];
            score = (e / denom2) / nz;         // probs / Exp(1) noise
            bidx = tok;
        }
        // argmax, tie -> smaller token index (matches jnp first-occurrence)
        #pragma unroll
        for (int off = 1; off < 64; off <<= 1) {
            float os = __shfl_xor(score, off, 64);
            uint32_t oi = __shfl_xor(bidx, off, 64);
            if (os > score || (os == score && oi < bidx)) { score = os; bidx = oi; }
        }
        if (lane == 0) out[row] = (int)bidx;
    }
}

extern "C" void kernel_launch(void* const* d_in, const int* in_sizes, int n_in,
                              void* d_out, int out_size, void* d_ws, size_t ws_size,
                              hipStream_t stream) {
    const float* logits = (const float*)d_in[0];
    const int* kk       = (const int*)d_in[1];
    const float* pp     = (const float*)d_in[2];
    const float* noise  = (const float*)d_in[3];
    int* out            = (int*)d_out;

    uint32_t* ws_u   = (uint32_t*)d_ws;                       // 512*64 u32
    uint32_t* ws_idx = ws_u + (size_t)B_ROWS * BLOCKS_PER_ROW * 64; // 512*64 u32

    topk_partial_kernel<<<B_ROWS * BLOCKS_PER_ROW, K1_THREADS, 0, stream>>>(logits, ws_u, ws_idx);
    sample_kernel<<<B_ROWS, 256, 0, stream>>>(ws_u, ws_idx, kk, pp, noise, out);
}

// Round 2
// 72.230 us; speedup vs baseline: 2.9699x; 2.9699x over previous
//
#include <hip/hip_runtime.h>
#include <stdint.h>

#define B_ROWS 128
#define V_COLS 128000
#define BPR 16                       // blocks per row
#define SLICE (V_COLS / BPR)         // 8000 floats
#define N4 (SLICE / 4)               // 2000 float4
#define K1_THREADS 256
#define LPT 8                        // float4 loads per thread (8*256 = 2048 >= 2000)
#define CAP 2048

// monotone transform: larger float <-> larger uint
__device__ __forceinline__ uint32_t f2u(float f) {
    uint32_t x = __float_as_uint(f);
    return (x & 0x80000000u) ? ~x : (x | 0x80000000u);
}
__device__ __forceinline__ float u2f(uint32_t u) {
    uint32_t x = (u & 0x80000000u) ? (u & 0x7FFFFFFFu) : ~u;
    return __uint_as_float(x);
}

// descending bitonic sort of (u, idx) in LDS; ties: larger idx first
// (matches stable ascending argsort of the reference when viewed descending)
__device__ __forceinline__ void bitonic_sort_desc(uint32_t* su, uint32_t* si, int NP) {
    const int tid = threadIdx.x;
    const int nth = blockDim.x;
    for (int ksz = 2; ksz <= NP; ksz <<= 1) {
        for (int j = ksz >> 1; j > 0; j >>= 1) {
            __syncthreads();
            for (int i = tid; i < NP; i += nth) {
                int ixj = i ^ j;
                if (ixj > i) {
                    uint32_t ua = su[i], ub = su[ixj];
                    uint32_t ia = si[i], ib = si[ixj];
                    bool a_lt = (ua < ub) || (ua == ub && ia < ib);
                    if (((i & ksz) == 0) ? a_lt : !a_lt) {
                        su[i] = ub; su[ixj] = ua;
                        si[i] = ib; si[ixj] = ia;
                    }
                }
            }
        }
    }
    __syncthreads();
}

// K1: per (row, 1/16-slice) block: exact top-64 pairs of the slice.
__global__ __launch_bounds__(K1_THREADS) void topk_slice_kernel(
    const float* __restrict__ logits,
    uint32_t* __restrict__ out_u, uint32_t* __restrict__ out_idx)
{
    __shared__ uint32_t s_u[CAP];
    __shared__ uint32_t s_i[CAP];
    __shared__ uint32_t s_T[4];
    __shared__ int s_cnt;

    const int blk = blockIdx.x;
    const int row = blk >> 4;
    const int q   = blk & 15;
    const int tid = threadIdx.x;
    const int lane = tid & 63;
    const int wv = tid >> 6;
    const float4* src = (const float4*)(logits + (size_t)row * V_COLS + (size_t)q * SLICE);

    if (tid == 0) s_cnt = 0;

    // ---- load slice into registers (static unroll; no scratch) ----
    uint32_t u[LPT * 4];
    #pragma unroll
    for (int i = 0; i < LPT; ++i) {
        const int i4 = i * K1_THREADS + tid;
        if (i4 < N4) {
            float4 v4 = src[i4];
            u[i * 4 + 0] = f2u(v4.x);
            u[i * 4 + 1] = f2u(v4.y);
            u[i * 4 + 2] = f2u(v4.z);
            u[i * 4 + 3] = f2u(v4.w);
        } else {
            u[i * 4 + 0] = 0u; u[i * 4 + 1] = 0u;
            u[i * 4 + 2] = 0u; u[i * 4 + 3] = 0u;
        }
    }

    // ---- per-thread max ----
    uint32_t mx = 0u;
    #pragma unroll
    for (int j = 0; j < LPT * 4; ++j) mx = (u[j] > mx) ? u[j] : mx;

    // ---- per-wave register bitonic sort (ascending) of the 64 thread-maxes ----
    uint32_t v = mx;
    #pragma unroll
    for (int ksz = 2; ksz <= 64; ksz <<= 1) {
        #pragma unroll
        for (int j = ksz >> 1; j > 0; j >>= 1) {
            uint32_t o = (uint32_t)__shfl_xor((int)v, j, 64);
            bool asc   = (lane & ksz) == 0;
            bool lower = (lane & j) == 0;
            uint32_t mn = (v < o) ? v : o;
            uint32_t mh = (v < o) ? o : v;
            v = (asc == lower) ? mn : mh;
        }
    }
    // lane 48 holds the 16th-largest thread-max of this wave
    uint32_t Tw = (uint32_t)__shfl((int)v, 48, 64);
    if (lane == 0) s_T[wv] = Tw;
    __syncthreads();
    uint32_t T0 = s_T[0] < s_T[1] ? s_T[0] : s_T[1];
    uint32_t T1 = s_T[2] < s_T[3] ? s_T[2] : s_T[3];
    uint32_t T = T0 < T1 ? T0 : T1;   // >=64 elements of the slice are >= T

    // ---- append candidates (expected ~90 per block) ----
    #pragma unroll
    for (int i = 0; i < LPT; ++i) {
        #pragma unroll
        for (int e = 0; e < 4; ++e) {
            uint32_t uv = u[i * 4 + e];
            if (uv >= T && uv != 0u) {
                int pos = atomicAdd(&s_cnt, 1);
                if (pos < CAP) {
                    s_u[pos] = uv;
                    s_i[pos] = (uint32_t)(q * SLICE + (i * K1_THREADS + tid) * 4 + e);
                }
            }
        }
    }
    __syncthreads();
    int cnt = s_cnt; if (cnt > CAP) cnt = CAP;
    int NP = 64; while (NP < cnt) NP <<= 1;
    for (int i = cnt + tid; i < NP; i += K1_THREADS) { s_u[i] = 0u; s_i[i] = 0xFFFFFFFFu; }
    bitonic_sort_desc(s_u, s_i, NP);   // leading barrier inside covers padding writes

    if (tid < 64) {
        out_u[blk * 64 + tid]   = s_u[tid];
        out_idx[blk * 64 + tid] = s_i[tid];
    }
}

// K2: one block per row: merge 16x64 candidates, sort, top-k/top-p filter, sample.
__global__ __launch_bounds__(256) void sample_kernel(
    const uint32_t* __restrict__ in_u, const uint32_t* __restrict__ in_idx,
    const int* __restrict__ kk, const float* __restrict__ pp,
    const float* __restrict__ noise, int* __restrict__ out)
{
    __shared__ uint32_t s_u[BPR * 64];
    __shared__ uint32_t s_i[BPR * 64];
    const int row = blockIdx.x;
    const int tid = threadIdx.x;

    #pragma unroll
    for (int i = 0; i < (BPR * 64) / 256; ++i) {
        int idx = i * 256 + tid;
        s_u[idx] = in_u[row * (BPR * 64) + idx];
        s_i[idx] = in_idx[row * (BPR * 64) + idx];
    }
    bitonic_sort_desc(s_u, s_i, BPR * 64);   // leading barrier covers loads

    if (tid < 64) {
        const int lane = tid;
        float v = u2f(s_u[lane]);             // lane j holds (j+1)-th largest of row
        uint32_t tok = s_i[lane];
        int k = kk[row];
        if (k > 64) k = 64;                    // safety; setup guarantees k<=63
        float p = pp[row];

        // top-k: threshold = k-th largest; keep v >= thr (ties kept, as reference)
        float thrv = __shfl(v, k - 1, 64);
        bool kept = v >= thrv;
        float m = __shfl(v, 0, 64);            // row max
        float e = kept ? expf(v - m) : 0.0f;

        // softmax denom over kept
        float denom = e;
        #pragma unroll
        for (int off = 1; off < 64; off <<= 1) denom += __shfl_xor(denom, off, 64);
        float prob = e / denom;

        // ascending-inclusive cumsum == suffix sum over descending lanes
        float cums = prob;
        #pragma unroll
        for (int off = 1; off < 64; off <<= 1) {
            float o = __shfl_down(cums, off, 64);
            cums += (lane + off < 64) ? o : 0.0f;
        }
        // top-p: mask cumsum <= 1-p, but always keep the max (lane 0)
        bool masked = (cums <= 1.0f - p) && (lane != 0);
        bool surv = kept && !masked;

        // renormalize over survivors
        float e2 = surv ? e : 0.0f;
        float denom2 = e2;
        #pragma unroll
        for (int off = 1; off < 64; off <<= 1) denom2 += __shfl_xor(denom2, off, 64);

        float score = -1.0f;
        uint32_t bidx = 0xFFFFFFFFu;
        if (surv) {
            float nz = noise[(size_t)row * V_COLS + tok];
            score = (e / denom2) / nz;         // probs / Exp(1) noise
            bidx = tok;
        }
        // argmax, tie -> smaller token index (matches jnp first-occurrence)
        #pragma unroll
        for (int off = 1; off < 64; off <<= 1) {
            float os = __shfl_xor(score, off, 64);
            uint32_t oi = __shfl_xor(bidx, off, 64);
            if (os > score || (os == score && oi < bidx)) { score = os; bidx = oi; }
        }
        if (lane == 0) out[row] = (int)bidx;
    }
}

extern "C" void kernel_launch(void* const* d_in, const int* in_sizes, int n_in,
                              void* d_out, int out_size, void* d_ws, size_t ws_size,
                              hipStream_t stream) {
    const float* logits = (const float*)d_in[0];
    const int* kk       = (const int*)d_in[1];
    const float* pp     = (const float*)d_in[2];
    const float* noise  = (const float*)d_in[3];
    int* out            = (int*)d_out;

    uint32_t* ws_u   = (uint32_t*)d_ws;                            // 2048*64 u32
    uint32_t* ws_idx = ws_u + (size_t)B_ROWS * BPR * 64;           // 2048*64 u32

    topk_slice_kernel<<<B_ROWS * BPR, K1_THREADS, 0, stream>>>(logits, ws_u, ws_idx);
    sample_kernel<<<B_ROWS, 256, 0, stream>>>(ws_u, ws_idx, kk, pp, noise, out);
}